// Round 9
// baseline (103.099 us; speedup 1.0000x reference)
//
#include <hip/hip_runtime.h>
#include <math.h>

// EvidNets R22: 1024-thr/16-wave blocks (4 waves/SIMD), 32 samples x ALL 512
// protos, single phase. Two dispatches, no cross-block sync.
//   A_c(b) = prod_k (1 - s_kb*(1-U_kc)),  N(b) = prod_k (1 - s_kb)
//   out[b][c<20] = (A_c-N)/K, out[b][20] = N/K, K = sum_c A_c - 19N
//   s_kb = alphap_k * exp(-gamma_k^2*(0.5*(|W_k|^2+|x_b|^2) - W_k.x_b))
// R21 post-mortem: 97.9us best; evid64 ~45us vs ~6us/SIMD issue floor.
// Occupancy 20% = 2 waves/SIMD (512-thr block + 149KB LDS) -> ds_read/L2
// latency chains exposed; lockstep (R20) and SMEM (R21) fixes each small.
// R22 structural fix: 16-wave workgroup FORCES 16 waves/CU residency =
// 4 waves/SIMD. Block = 32 samples (A 32KB) x 512 protos (sc 64KB) +
// per-wave VS slices (40KB) = 137KB. Wave wv owns protos wv*32..+32, ONE
// pass (48 MFMA), writes its swizzled 32x32 s-band, combines with ALL 64
// lanes (lane = sample x proto-half, shfl_xor(32) merge per class).
// Ring depth 4 (TLP hides L2 now; keeps live VGPR ~115 <= the HARD 128
// cap of 16 resident waves). R15 redux guard: amdgpu_waves_per_eu(4,4)
// pins the allocator at 128 (R15's 1024-thr failure was the default
// 8-waves/EU target -> 64 VGPR -> spills). Tripwire: VGPR=64 or
// FETCH >> 10.7MB means the cap returned.
// No inter-wave barriers in the body (s-band + VS slice wave-private);
// B1 after staging, B5 before endgame (aliases pool).

#define NBATCH 16384
#define ND     256
#define NP     512
#define NCLS   20
#define OC     21

typedef short  short8  __attribute__((ext_vector_type(8)));
typedef short  short4v __attribute__((ext_vector_type(4)));
typedef unsigned short ushort8 __attribute__((ext_vector_type(8)));
typedef float  f32x16  __attribute__((ext_vector_type(16)));

// ---- workspace layout (bytes) ----
#define OFF_PWH 0u
#define OFF_PWL 262144u
#define OFF_VS  524288u                 // float VS[21][512] = 1-U (row 20 = 1)
#define OFF_WQ  567296u
#define OFF_AP  569344u
#define OFF_G2  571392u

__device__ __forceinline__ unsigned short f2bf_rn(float f) {
  unsigned int u = __float_as_uint(f);
  unsigned int r = (u + 0x7FFFu + ((u >> 16) & 1u)) >> 16;   // RNE (finite inputs)
  return (unsigned short)r;
}
__device__ __forceinline__ float bf2f(unsigned short h) {
  return __uint_as_float(((unsigned int)h) << 16);
}

// Combined prep: blocks 0..63 pack W[512][256] -> MFMA B-fragment order hi/lo
// bf16 + row sum-squares; blocks 64..65 build VS/AP/G2 tables.
// frag elem (tile,step,lane,j) = src[tile*32+(lane&31)][step*16+8*(lane>>5)+j]
__global__ __launch_bounds__(256)
void prep(const float* __restrict__ Wsrc, const float* __restrict__ BETA,
          const float* __restrict__ alpha, const float* __restrict__ gamma,
          unsigned short* __restrict__ dh, unsigned short* __restrict__ dl,
          float* __restrict__ sq, float* __restrict__ VS,
          float* __restrict__ AP, float* __restrict__ G2)
{
  const int bid = blockIdx.x;
  if (bid < 64) {                      // ---- pack W ----
    const int tid = bid * 256 + threadIdx.x;
    const int row = tid >> 5, seg = tid & 31;
    const float4* s4 = (const float4*)(Wsrc + (size_t)row * ND + seg * 8);
    const float4 a = s4[0], b = s4[1];
    const float v[8] = {a.x, a.y, a.z, a.w, b.x, b.y, b.z, b.w};
    ushort8 hv, lv;
    float ssq = 0.f;
    #pragma unroll
    for (int j = 0; j < 8; ++j) {
      ssq = fmaf(v[j], v[j], ssq);
      const unsigned short hh = f2bf_rn(v[j]);
      hv[j] = hh;
      lv[j] = f2bf_rn(v[j] - bf2f(hh));
    }
    const int tile = row >> 5, m = row & 31, step = seg >> 1, r = seg & 1;
    const size_t cidx = (size_t)(tile * 16 + step) * 64 + m + 32 * r;
    *(ushort8*)(dh + cidx * 8) = hv;
    *(ushort8*)(dl + cidx * 8) = lv;
    #pragma unroll
    for (int off = 1; off < 32; off <<= 1) ssq += __shfl_xor(ssq, off, 64);
    if (seg == 0) sq[row] = ssq;
  } else {                             // ---- scalar tables ----
    const int k = (bid - 64) * 256 + threadIdx.x;
    if (k >= NP) return;
    float bv[NCLS], bs = 0.f;
    #pragma unroll
    for (int c = 0; c < NCLS; ++c) { bv[c] = BETA[k * NCLS + c]; bs = fmaf(bv[c], bv[c], bs); }
    const float binv = 1.f / bs;
    #pragma unroll
    for (int c = 0; c < NCLS; ++c) VS[c * NP + k] = 1.f - bv[c] * bv[c] * binv;
    VS[NCLS * NP + k] = 1.f;
    AP[k] = 0.99f / (1.f + __expf(-alpha[k]));
    const float g = gamma[k];
    G2[k] = g * g;
  }
}

// One MFMA pass over the block's 32-sample A-tile vs one 32-proto B-tile:
// K=256, hi/lo split in TWO acc chains (accA = ah*bh; accB = ah*bl + al*bh),
// depth-4 B ring (TLP at 4 waves/SIMD hides L2), epilogue s -> sout[16].
__device__ __forceinline__ void mfma_pass4(
    const short* __restrict__ Ah, const short* __restrict__ Al,
    const short8* __restrict__ bHc, const short8* __restrict__ bLc,
    const int lane, const float* __restrict__ xqs,
    const float wqk, const float apk, const float g2k, float* __restrict__ sout)
{
  short8 wbh[4], wbl[4];
  #pragma unroll
  for (int p = 0; p < 4; ++p) { wbh[p] = bHc[p * 64]; wbl[p] = bLc[p * 64]; }

  f32x16 accA, accB;
  #pragma unroll
  for (int i = 0; i < 16; ++i) { accA[i] = 0.f; accB[i] = 0.f; }
  const short8* aH = (const short8*)Ah + lane;
  const short8* aL = (const short8*)Al + lane;
  #pragma unroll
  for (int step = 0; step < 16; ++step) {
    const short8 ah = aH[step * 64], al = aL[step * 64];
    const short8 bh = wbh[step & 3], bl = wbl[step & 3];
    if (step < 12) {
      wbh[step & 3] = bHc[(step + 4) * 64];
      wbl[step & 3] = bLc[(step + 4) * 64];
    }
    accA = __builtin_amdgcn_mfma_f32_32x32x16_bf16(ah, bh, accA, 0, 0, 0);
    accB = __builtin_amdgcn_mfma_f32_32x32x16_bf16(ah, bl, accB, 0, 0, 0);
    accB = __builtin_amdgcn_mfma_f32_32x32x16_bf16(al, bh, accB, 0, 0, 0);
  }
  // C/D: col(n)=lane&31 (proto), row(m)=(rg&3)+8*(rg>>2)+4*(lane>>5)
  const int h = lane >> 5;
  #pragma unroll
  for (int rg = 0; rg < 16; ++rg) {
    const int   m  = (rg & 3) + 8 * (rg >> 2) + 4 * h;
    const float dv = 0.5f * (wqk + xqs[m]) - (accA[rg] + accB[rg]);
    sout[rg] = apk * __expf(-g2k * dv);
  }
}

// ---- main: 512 blocks x 1024 thr (16 waves, 4/SIMD). Block bx: samples
// bx*32..+32, ALL 512 protos, one pass per wave. LDS: A 32KB [0,32K) +
// sc[32][512] 64KB [32K,96K) + vsl 40KB + xqs; endgame aliases pool. ----
__global__ __launch_bounds__(1024) __attribute__((amdgpu_waves_per_eu(4, 4)))
void evid32w(const float* __restrict__ X,
             const unsigned short* __restrict__ PWH, const unsigned short* __restrict__ PWL,
             const float* __restrict__ VS, const float* __restrict__ WQ,
             const float* __restrict__ AP, const float* __restrict__ G2,
             float* __restrict__ OUT)
{
  __shared__ __align__(16) char pool[98304];
  __shared__ float vsl[16 * NCLS * 32];  // per-wave private VS slices (40KB)
  __shared__ float xqs[32];
  short* Ah = (short*)pool;            // 8192 shorts = 16KB
  short* Al = (short*)(pool + 16384);  // 8192 shorts = 16KB
  float* sc = (float*)(pool + 32768);  // 32 x 512 floats = 64KB

  const int t    = threadIdx.x;
  const int lane = t & 63;
  const int wv   = __builtin_amdgcn_readfirstlane(t >> 6);  // wave 0..15
  const int bx   = blockIdx.x;
  const int bbase = bx * 32;
  const int pl = lane & 31, h = lane >> 5;

  // ---- stage: 32 X rows f32 -> hi/lo bf16 fragments (32 lanes/row) ----
  {
    const int r  = t >> 5;             // 0..31 (row = wv*2 + (lane>>5))
    const int sg = t & 31;             // 8 cols per lane
    const float* xrow = X + (size_t)(bbase + r) * ND;
    float ssq = 0.f;
    #pragma unroll
    for (int it = 0; it < 2; ++it) {
      const int c0 = sg * 8 + it * 4;
      const float4 v = *(const float4*)(xrow + c0);
      const float vv[4] = {v.x, v.y, v.z, v.w};
      short4v h4, l4;
      #pragma unroll
      for (int j = 0; j < 4; ++j) {
        ssq = fmaf(vv[j], vv[j], ssq);
        const unsigned short hh = f2bf_rn(vv[j]);
        h4[j] = (short)hh;
        l4[j] = (short)f2bf_rn(vv[j] - bf2f(hh));
      }
      const int step = c0 >> 4, hf = (c0 >> 3) & 1, j0 = c0 & 7;
      const int base = (step * 64 + r + 32 * hf) * 8 + j0;
      *(short4v*)&Ah[base] = h4;
      *(short4v*)&Al[base] = l4;
    }
    // reduce over the 32 lanes of this row (lanes 0-31 / 32-63 are distinct rows)
    ssq += __shfl_xor(ssq, 1, 64);
    ssq += __shfl_xor(ssq, 2, 64);
    ssq += __shfl_xor(ssq, 4, 64);
    ssq += __shfl_xor(ssq, 8, 64);
    ssq += __shfl_xor(ssq, 16, 64);
    if (sg == 0) xqs[r] = ssq;
  }
  __syncthreads();                     // B1: A-frags + xqs ready

  // ---- stage this wave's VS slice (hidden under MFMA below) ----
  float* vw = vsl + wv * (NCLS * 32);
  {
    const float* vg = VS + wv * 32;    // + c*NP
    #pragma unroll
    for (int i = 0; i < 10; ++i) {
      const int idx = i * 64 + lane;   // 0..639 = c*32+j
      vw[idx] = vg[(idx >> 5) * NP + (idx & 31)];
    }
  }

  // per-lane prototype params (L2-resident)
  const int kp = wv * 32 + pl;
  const float wqk = WQ[kp], apk = AP[kp], g2k = G2[kp];
  const short8* bHc = (const short8*)PWH + (size_t)wv * 1024 + lane;
  const short8* bLc = (const short8*)PWL + (size_t)wv * 1024 + lane;

  float sreg[16];
  mfma_pass4(Ah, Al, bHc, bLc, lane, xqs, wqk, apk, g2k, sreg);

  // write s-band: sc[m][(p + 4m) & 511], p = wv*32+pl (bands disjoint)
  {
    const int p = wv * 32 + pl;
    #pragma unroll
    for (int rg = 0; rg < 16; ++rg) {
      const int m = (rg & 3) + 8 * (rg >> 2) + 4 * h;
      sc[m * 512 + ((p + 4 * m) & 511)] = sreg[rg];
    }
  }
  // no barrier: own band only; within-wave LDS ordering via lgkmcnt

  // ---- combine: lane = (sample pl, proto-half h -> 16 protos each) ----
  float Apc[OC];
  {
    float sv[16];
    const int cb = wv * 32 + h * 16 + 4 * pl;   // swizzled col base
    #pragma unroll
    for (int q = 0; q < 4; ++q)
      *(float4*)&sv[4 * q] = *(const float4*)&sc[pl * 512 + ((cb + 4 * q) & 511)];
    // sv[4q+r] = s[sample pl][proto wv*32 + h*16 + 4q + r]

    const float* vb = vw + h * 16;
    #pragma unroll 4
    for (int c = 0; c < NCLS; ++c) {
      const float* vp = vb + c * 32;              // LDS broadcast reads
      float f4[4];
      #pragma unroll
      for (int j = 0; j < 4; ++j) f4[j] = fmaf(-sv[j], vp[j], 1.0f);
      #pragma unroll
      for (int j = 4; j < 16; ++j) f4[j & 3] *= fmaf(-sv[j], vp[j], 1.0f);
      Apc[c] = (f4[0] * f4[1]) * (f4[2] * f4[3]);
    }
    { // c = 20: VS row == 1.0 -> f = 1 - s
      float f4[4];
      #pragma unroll
      for (int j = 0; j < 4; ++j) f4[j] = 1.0f - sv[j];
      #pragma unroll
      for (int j = 4; j < 16; ++j) f4[j & 3] *= (1.0f - sv[j]);
      Apc[NCLS] = (f4[0] * f4[1]) * (f4[2] * f4[3]);
    }
    // merge proto-halves: lanes pl and pl+32 hold the two 16-proto partials
    #pragma unroll
    for (int c = 0; c < OC; ++c) Apc[c] *= __shfl_xor(Apc[c], 32, 64);
  }
  __syncthreads();                     // B5: all waves done with A/sc regions

  // ---- endgame: reduce 16 wave-partials, normalize, store OUT in-block ----
  float* E  = (float*)pool;            // 16*21*32 floats = 43008 B
  float* R  = (float*)(pool + 43008);  // 21*32 floats
  float* kv = (float*)(pool + 53760);  // 32 floats
  if (h == 0) {
    #pragma unroll
    for (int c = 0; c < OC; ++c) E[(wv * OC + c) * 32 + pl] = Apc[c];
  }
  __syncthreads();
  {
    const int b = t & 31, j = t >> 5;  // j = 0..31
    if (j < OC) {
      float p = E[j * 32 + b];
      #pragma unroll
      for (int w = 1; w < 16; ++w) p *= E[(w * OC + j) * 32 + b];
      R[j * 32 + b] = p;
    }
  }
  __syncthreads();
  if (t < 32) {
    const float Nv = R[NCLS * 32 + t];
    float K = Nv;
    #pragma unroll
    for (int c = 0; c < NCLS; ++c) K += R[c * 32 + t] - Nv;
    kv[t] = 1.0f / K;
  }
  __syncthreads();
  if (t < 32 * OC) {
    const int b = t / OC, c = t - b * OC;
    const float Nv = R[NCLS * 32 + b];
    const float ik = kv[b];
    OUT[(size_t)bx * 32 * OC + t] = (c < NCLS) ? (R[c * 32 + b] - Nv) * ik : Nv * ik;
  }
}

extern "C" void kernel_launch(void* const* d_in, const int* in_sizes, int n_in,
                              void* d_out, int out_size, void* d_ws, size_t ws_size,
                              hipStream_t stream) {
  (void)in_sizes; (void)n_in; (void)out_size; (void)ws_size;
  const float* X     = (const float*)d_in[0];
  const float* Wm    = (const float*)d_in[1];
  const float* BETA  = (const float*)d_in[2];
  const float* ALPHA = (const float*)d_in[3];
  const float* GAMMA = (const float*)d_in[4];
  float* OUT = (float*)d_out;

  char* ws = (char*)d_ws;
  unsigned short* PWH = (unsigned short*)(ws + OFF_PWH);
  unsigned short* PWL = (unsigned short*)(ws + OFF_PWL);
  float* VS = (float*)(ws + OFF_VS);
  float* WQ = (float*)(ws + OFF_WQ);
  float* AP = (float*)(ws + OFF_AP);
  float* G2 = (float*)(ws + OFF_G2);

  hipLaunchKernelGGL(prep, dim3(66), dim3(256), 0, stream,
                     Wm, BETA, ALPHA, GAMMA, PWH, PWL, WQ, VS, AP, G2);
  hipLaunchKernelGGL(evid32w, dim3(NBATCH / 32), dim3(1024), 0, stream,
                     X, PWH, PWL, VS, WQ, AP, G2, OUT);
}